// Round 9
// baseline (393.741 us; speedup 1.0000x reference)
//
#include <hip/hip_runtime.h>

#define BATCH 65536

typedef __attribute__((ext_vector_type(8))) short bf16x8;
typedef __attribute__((ext_vector_type(4))) float f32x4;

__device__ __forceinline__ unsigned short f2bf(float f) {
  unsigned int u = __float_as_uint(f);
  u += 0x7fffu + ((u >> 16) & 1u);   // RNE (one-time weight builds only)
  return (unsigned short)(u >> 16);
}
// trunc-pack 2 floats -> 1 dword of 2 bf16 (lo in low half), single v_perm_b32
__device__ __forceinline__ unsigned pack_trunc(float lo, float hi) {
  return __builtin_amdgcn_perm(__float_as_uint(hi), __float_as_uint(lo), 0x07060302u);
}

// tanh(o)*sigmoid(u): 2 exp + 1 rcp; lower-bound clamps keep it NaN-proof.
__device__ __forceinline__ float gru_act(float u, float o) {
  u = fmaxf(u, -60.0f);
  o = fmaxf(o, -30.0f);
  float a  = __expf(-u);
  float a2 = __expf(-2.0f * o);
  return (1.0f - a2) * __builtin_amdgcn_rcpf((1.0f + a) * (1.0f + a2));
}

// conv 3x3 SAME on 3x3 grid, unrolled tap value
__device__ __forceinline__ float conv_tap(const float* __restrict__ w, int co, int ci,
                                          int p, int q, int CINTOT) {
  int pi = p / 3, pj = p % 3, qi = q / 3, qj = q % 3;
  int di = qi - pi + 1, dj = qj - pj + 1;
  if ((unsigned)di < 3u && (unsigned)dj < 3u)
    return w[((co * CINTOT + ci) * 3 + di) * 3 + dj];
  return 0.0f;
}

// BT[g][n][k] bf16, n = co*9+p, k = ci*9+q
__global__ void build_bt(const float* __restrict__ wu, const float* __restrict__ wo,
                         unsigned short* __restrict__ BT, int COUT, int CINX, int CINTOT) {
  int NG = COUT * 9, K = CINX * 9;
  int total = 2 * NG * K;
  int e = blockIdx.x * 256 + threadIdx.x;
  if (e >= total) return;
  int g = e / (NG * K);
  int rem = e - g * (NG * K);
  int n = rem / K, k = rem - n * K;
  BT[e] = f2bf(conv_tap(g ? wo : wu, n / 9, k / 9, n % 9, k % 9, CINTOT));
}

// A1 transposed: [g][q][c], c = col n in [0,288), q = input tap in [0,9)
__global__ void build_a1(const float* __restrict__ wu, const float* __restrict__ wo,
                         float* __restrict__ A1) {
  int e = blockIdx.x * 256 + threadIdx.x;
  if (e >= 5184) return;
  int g = e / 2592;
  int rem = e - g * 2592;
  int q = rem / 288, c = rem - q * 288;
  A1[e] = conv_tap(g ? wo : wu, c / 9, 0, c % 9, q, 33);
}

// ---------------- LDS layout (bytes), lifetimes barrier-separated ----------------
// [0,40960)     x1l (L1 write .. L2 reads) | x3l [0,18688) (L3 epi .. dense)
// [20480,25664) wl  (post-L2 .. dense)  [25664,25700) blb   (disjoint from x3l)
// [40960,44288) xl 64 x 13 f32 (L1 only)
#define OFF_X1L 0
#define OFF_X3L 0
#define OFF_WL 20480
#define OFF_BLB 25664
#define OFF_XL 40960
#define SMEM_BYTES 44288

__global__ __launch_bounds__(512, 4) void megafused(
    const float* __restrict__ xin, const float* __restrict__ A1,
    const float* __restrict__ b1u, const float* __restrict__ b1o,
    const unsigned short* __restrict__ BT2,
    const float* __restrict__ b2u, const float* __restrict__ b2o,
    const unsigned short* __restrict__ BT3,
    const float* __restrict__ b3u, const float* __restrict__ b3o,
    const float* __restrict__ wd, const float* __restrict__ bd,
    float* __restrict__ x1, float* __restrict__ x2,
    float* __restrict__ x3, float* __restrict__ out) {
  __shared__ __align__(16) char smem[SMEM_BYTES];
  char* x1l = smem + OFF_X1L;
  unsigned short* x3l = (unsigned short*)(smem + OFF_X3L);
  float* xl = (float*)(smem + OFF_XL);
  float* wl = (float*)(smem + OFF_WL);
  float* blb = (float*)(smem + OFF_BLB);

  const int tid = threadIdx.x;
  const int lane = tid & 63;
  const int wid = tid >> 6;          // 0..7
  const int lrow = lane & 15;
  const int jc = (lane >> 4) & 3;
  const int mh = wid >> 2;           // row half
  const int cg = wid & 3;            // col group
  const int r0 = blockIdx.x * 64;

  // L2 B-frag per-lane byte offsets into BT2 (row stride 576B; gate stride 331776B)
  unsigned bvoff[3];
#pragma unroll
  for (int f = 0; f < 3; ++f)
    bvoff[f] = (unsigned)(((cg * 3 + f) * 16 + lrow) * 576 + jc * 16);
  const char* BT2b = (const char*)BT2;

  // stage x input (stride 13 floats)
  for (int c = tid; c < 576; c += 512) xl[(c / 9) * 13 + (c % 9)] = xin[(size_t)r0 * 9 + c];
  __syncthreads();

  // preload L2 step-0 B frags (in flight across all of L1)
  bf16x8 bA[2][3], bB[2][3];
#pragma unroll
  for (int g = 0; g < 2; ++g)
#pragma unroll
    for (int f = 0; f < 3; ++f)
      bA[g][f] = *(const bf16x8*)(BT2b + g * 331776u + bvoff[f]);

  // ---- L1: exact fp32. 1152 units = 288 cols x 4 row-quarters ----
  for (int uu = 0; uu < 3; ++uu) {
    int u = tid + (uu << 9);
    if (u < 1152) {
      int c = u >> 2, rq = u & 3;
      float au[9], ao[9];
#pragma unroll
      for (int q = 0; q < 9; ++q) {
        au[q] = A1[q * 288 + c];
        ao[q] = A1[2592 + q * 288 + c];
      }
      float bU = b1u[c / 9], bO = b1o[c / 9];
      const int cbase = c >> 3, cb = (c & 7) * 2;
#pragma unroll 4
      for (int i = 0; i < 16; ++i) {
        int r = (rq << 4) + i;
        const float4 xv0 = *(const float4*)&xl[r * 13];
        const float4 xv1 = *(const float4*)&xl[r * 13 + 4];
        const float x8 = xl[r * 13 + 8];
        float uacc = bU, oacc = bO;
        uacc = fmaf(au[0], xv0.x, uacc); oacc = fmaf(ao[0], xv0.x, oacc);
        uacc = fmaf(au[1], xv0.y, uacc); oacc = fmaf(ao[1], xv0.y, oacc);
        uacc = fmaf(au[2], xv0.z, uacc); oacc = fmaf(ao[2], xv0.z, oacc);
        uacc = fmaf(au[3], xv0.w, uacc); oacc = fmaf(ao[3], xv0.w, oacc);
        uacc = fmaf(au[4], xv1.x, uacc); oacc = fmaf(ao[4], xv1.x, oacc);
        uacc = fmaf(au[5], xv1.y, uacc); oacc = fmaf(ao[5], xv1.y, oacc);
        uacc = fmaf(au[6], xv1.z, uacc); oacc = fmaf(ao[6], xv1.z, oacc);
        uacc = fmaf(au[7], xv1.w, uacc); oacc = fmaf(ao[7], xv1.w, oacc);
        uacc = fmaf(au[8], x8, uacc);    oacc = fmaf(ao[8], x8, oacc);
        float v = gru_act(uacc, oacc);
        x1[(size_t)(r0 + r) * 288 + c] = v;
        *(unsigned short*)(x1l + r * 640 + ((cbase ^ (r & 7)) << 4) + cb) =
            (unsigned short)(__float_as_uint(v) >> 16);
      }
    }
  }
  __syncthreads();   // x1l visible to all waves

  // ---- L2: x1l(bf16) x BT2(global->reg) -> x2 fp32. BARRIER-FREE 27 steps ----
  {
    const char* aBase[2];
    int aXor[2];
#pragma unroll
    for (int m = 0; m < 2; ++m) {
      int row = mh * 32 + m * 16 + lrow;
      aBase[m] = x1l + row * 640;
      aXor[m] = row & 7;
    }

    f32x4 acc[2][2][3] = {};
    auto step = [&](int s, bf16x8 (&cur)[2][3], bf16x8 (&nxt)[2][3]) {
      const int kt = s % 9, nch = s / 9;
      // issue loads for step s+1 (no barrier ever drains them early)
      if (s < 26) {
        const unsigned uoff =
            (unsigned)((s + 1) / 9) * 110592u + (unsigned)((s + 1) % 9) * 64u;
#pragma unroll
        for (int g = 0; g < 2; ++g)
#pragma unroll
          for (int f = 0; f < 3; ++f)
            nxt[g][f] = *(const bf16x8*)(BT2b + uoff + g * 331776u + bvoff[f]);
      }
      bf16x8 af[2];
      const int c8 = kt * 4 + jc;
#pragma unroll
      for (int m = 0; m < 2; ++m)
        af[m] = *(const bf16x8*)(aBase[m] + ((c8 ^ aXor[m]) << 4));
#pragma unroll
      for (int m = 0; m < 2; ++m)
#pragma unroll
        for (int g = 0; g < 2; ++g)
#pragma unroll
          for (int f = 0; f < 3; ++f)
            acc[m][g][f] = __builtin_amdgcn_mfma_f32_16x16x32_bf16(
                af[m], cur[g][f], acc[m][g][f], 0, 0, 0);
      if (kt == 8) {
        const int n0 = nch * 192;
#pragma unroll
        for (int m = 0; m < 2; ++m)
#pragma unroll
          for (int f = 0; f < 3; ++f) {
            int n = n0 + (cg * 3 + f) * 16 + lrow;
            float bU = b2u[n / 9], bO = b2o[n / 9];
            f32x4 uv = acc[m][0][f], ov = acc[m][1][f];
#pragma unroll
            for (int t = 0; t < 4; ++t) {
              int r = r0 + mh * 32 + m * 16 + jc * 4 + t;
              x2[(size_t)r * 576 + n] = gru_act(uv[t] + bU, ov[t] + bO);
            }
            acc[m][0][f] = (f32x4){0.f, 0.f, 0.f, 0.f};
            acc[m][1][f] = (f32x4){0.f, 0.f, 0.f, 0.f};
          }
      }
    };
#pragma unroll
    for (int s = 0; s < 27; ++s) {
      if (s & 1) step(s, bB, bA);
      else       step(s, bA, bB);
    }
  }
  __syncthreads();   // drains x2 stores before readback; x1l dead

  // stage dense weights (regions disjoint from x3l; read after post-L3 barrier)
  for (int c = tid; c < 1296; c += 512) wl[c] = wd[c];
  if (tid < 9) blb[tid] = bd[tid];

  // ---- L3: x2(global->reg, L2-hot) x BT3(global->reg). BARRIER-FREE 18 steps ----
  {
    // B offsets: N padded 144->192; cg==3 rows clamped in-bounds (results discarded)
    unsigned bvoff3[3];
#pragma unroll
    for (int f = 0; f < 3; ++f) {
      int nr = (cg * 3 + f) * 16 + lrow;
      if (cg == 3) nr -= 64;               // [80,128): valid rows, garbage, unused
      bvoff3[f] = (unsigned)(nr * 1152 + jc * 16);
    }
    const char* BT3b = (const char*)BT3;
    unsigned avoff[2];
#pragma unroll
    for (int m = 0; m < 2; ++m)
      avoff[m] = (unsigned)(((mh * 32 + m * 16 + lrow) * 576 + jc * 8) * 4);
    const char* x2b = (const char*)(x2 + (size_t)r0 * 576);

    f32x4 acc[2][2][3] = {};
#pragma unroll
    for (int kt = 0; kt < 18; ++kt) {
      bf16x8 bfr[2][3];
      const unsigned uB = (unsigned)kt * 64u;
#pragma unroll
      for (int g = 0; g < 2; ++g)
#pragma unroll
        for (int f = 0; f < 3; ++f)
          bfr[g][f] = *(const bf16x8*)(BT3b + uB + g * 165888u + bvoff3[f]);
      bf16x8 af[2];
      const unsigned uA = (unsigned)kt * 128u;
#pragma unroll
      for (int m = 0; m < 2; ++m) {
        float4 a0 = *(const float4*)(x2b + avoff[m] + uA);
        float4 a1 = *(const float4*)(x2b + avoff[m] + uA + 16);
        union { uint4 u; bf16x8 v; } cv;
        cv.u.x = pack_trunc(a0.x, a0.y);
        cv.u.y = pack_trunc(a0.z, a0.w);
        cv.u.z = pack_trunc(a1.x, a1.y);
        cv.u.w = pack_trunc(a1.z, a1.w);
        af[m] = cv.v;
      }
#pragma unroll
      for (int m = 0; m < 2; ++m)
#pragma unroll
        for (int g = 0; g < 2; ++g)
#pragma unroll
          for (int f = 0; f < 3; ++f)
            acc[m][g][f] = __builtin_amdgcn_mfma_f32_16x16x32_bf16(
                af[m], bfr[g][f], acc[m][g][f], 0, 0, 0);
    }
    // epilogue: cg<3 carry real cols (n<144): act -> x3 global + x3l (trunc)
    if (cg < 3) {
#pragma unroll
      for (int m = 0; m < 2; ++m)
#pragma unroll
        for (int f = 0; f < 3; ++f) {
          int n = (cg * 3 + f) * 16 + lrow;
          float bU = b3u[n / 9], bO = b3o[n / 9];
          f32x4 uv = acc[m][0][f], ov = acc[m][1][f];
#pragma unroll
          for (int t = 0; t < 4; ++t) {
            int r = mh * 32 + m * 16 + jc * 4 + t;
            float v = gru_act(uv[t] + bU, ov[t] + bO);
            x3[(size_t)(r0 + r) * 144 + n] = v;
            x3l[r * 146 + n] = (unsigned short)(__float_as_uint(v) >> 16);
          }
        }
    }
  }
  __syncthreads();   // x3l + wl ready

  // ---- dense head: 9 cols x 64 rows; wave j = col wid, plus wave0 col 8 ----
  {
    int row = lane;
    int j = wid;
    float s = blb[j];
    for (int k = 0; k < 144; k += 2) {
      unsigned pr = *(const unsigned*)&x3l[row * 146 + k];
      float v0 = __uint_as_float(pr << 16);
      float v1 = __uint_as_float(pr & 0xffff0000u);
      const float2 w0 = *(const float2*)&wl[j * 144 + k];
      s = fmaf(v0, w0.x, s);
      s = fmaf(v1, w0.y, s);
    }
    out[(size_t)(r0 + row) * 9 + j] = s;
    if (tid < 64) {
      float s8 = blb[8];
      for (int k = 0; k < 144; k += 2) {
        unsigned pr = *(const unsigned*)&x3l[row * 146 + k];
        float v0 = __uint_as_float(pr << 16);
        float v1 = __uint_as_float(pr & 0xffff0000u);
        const float2 w0 = *(const float2*)&wl[8 * 144 + k];
        s8 = fmaf(v0, w0.x, s8);
        s8 = fmaf(v1, w0.y, s8);
      }
      out[(size_t)(r0 + row) * 9 + 8] = s8;
    }
  }
}

extern "C" void kernel_launch(void* const* d_in, const int* in_sizes, int n_in,
                              void* d_out, int out_size, void* d_ws, size_t ws_size,
                              hipStream_t stream) {
  const float* inputs = (const float*)d_in[0];
  const float* wd  = (const float*)d_in[1];
  const float* bd  = (const float*)d_in[2];
  const float* w1u = (const float*)d_in[3];
  const float* b1u = (const float*)d_in[4];
  const float* w1o = (const float*)d_in[7];
  const float* b1o = (const float*)d_in[8];
  const float* w2u = (const float*)d_in[9];
  const float* b2u = (const float*)d_in[10];
  const float* w2o = (const float*)d_in[13];
  const float* b2o = (const float*)d_in[14];
  const float* w3u = (const float*)d_in[15];
  const float* b3u = (const float*)d_in[16];
  const float* w3o = (const float*)d_in[19];
  const float* b3o = (const float*)d_in[20];

  float* out = (float*)d_out;                    // [B][9]
  float* x1 = out + (size_t)BATCH * 9;           // [B][288]
  float* x2 = x1 + (size_t)BATCH * 288;          // [B][576]
  float* x3 = x2 + (size_t)BATCH * 576;          // [B][144]

  unsigned short* BT2 = (unsigned short*)d_ws;   // [2][576][288] bf16
  unsigned short* BT3 = BT2 + 331776;            // [2][144][576] bf16
  float* A1 = (float*)((char*)d_ws + 995328);    // [2][9][288] fp32

  build_bt<<<1296, 256, 0, stream>>>(w2u, w2o, BT2, 64, 32, 96);
  build_bt<<<648, 256, 0, stream>>>(w3u, w3o, BT3, 16, 64, 80);
  build_a1<<<21, 256, 0, stream>>>(w1u, w1o, A1);

  megafused<<<BATCH / 64, 512, 0, stream>>>(inputs, A1, b1u, b1o, BT2, b2u, b2o,
                                            BT3, b3u, b3o, wd, bd, x1, x2, x3, out);
}